// Round 6
// baseline (536.092 us; speedup 1.0000x reference)
//
#include <hip/hip_runtime.h>
#include <math.h>

// Shapes (fixed): H=8, D=256, HD=32, B=16, Q=512, S1=64, NTASK=448
typedef _Float16 f16;
typedef f16  f16x8 __attribute__((ext_vector_type(8)));
typedef f16  f16x4 __attribute__((ext_vector_type(4)));
typedef f16  f16x2 __attribute__((ext_vector_type(2)));
typedef float f32x4 __attribute__((ext_vector_type(4)));

// ---------------------------------------------------------------------------
// Projection GEMM (fp32 compute, fp16 output), merged column-quadrants.
// One block computes a 64-row x 256-col output tile for projection p
// (R6: was 4 separate blocks -> 4x fewer barriers, 4x less A staging,
//  64 FMA per 2+4 LDS reads per kk instead of 16 per 2; accumulation order
//  per output unchanged -> bitwise-identical results).
// Normal outputs: [h][b][n][32] fp16 row-major.  V output (p==vt_p): V^T
// layout [h][b][e][NR] fp16 (contiguous m) for MFMA B-fragments.
// ---------------------------------------------------------------------------
__global__ __launch_bounds__(256)
void proj_gemm(const float* __restrict__ A,
               const float* __restrict__ W0, const float* __restrict__ W1p,
               const float* __restrict__ W2p, const float* __restrict__ W3p,
               f16* __restrict__ O0, f16* __restrict__ O1,
               f16* __restrict__ O2, f16* __restrict__ O3,
               int q_off, int rows_per_b, int tiles_per_b, int vt_p)
{
    __shared__ float Asub[32][68];
    __shared__ float Bsub[32][256];
    const int tid = (int)threadIdx.x;
    const int b  = (int)blockIdx.x / tiles_per_b;
    const int n0 = ((int)blockIdx.x % tiles_per_b) * 64;
    const int p  = (int)blockIdx.y;
    const float* Wp = (p == 0) ? W0 : (p == 1) ? W1p : (p == 2) ? W2p : W3p;
    f16* Op         = (p == 0) ? O0 : (p == 1) ? O1 : (p == 2) ? O2 : O3;

    const int tx = tid & 15, ty = tid >> 4;
    float acc[4][4][4] = {};                 // [cb][row i][col j] -> registers
    const float* Arow = A + (size_t)(b * 512 + q_off + n0) * 256;

    // B staging: thread tid owns column tid (h = tid>>5, e = tid&31)
    const int ch = tid >> 5, ce = tid & 31;

    for (int k0 = 0; k0 < 256; k0 += 32) {
        #pragma unroll
        for (int i = 0; i < 8; ++i) {
            int idx = tid + 256 * i;
            int kk = idx & 31, r = idx >> 5;
            Asub[kk][r] = Arow[(size_t)r * 256 + k0 + kk];
        }
        {
            const float* wb = Wp + (size_t)(ch * 256 + k0) * 32 + ce;
            #pragma unroll
            for (int kk = 0; kk < 32; ++kk)
                Bsub[kk][tid] = wb[kk * 32];
        }
        __syncthreads();
        #pragma unroll 4
        for (int kk = 0; kk < 32; ++kk) {
            float4 a4 = *(const float4*)&Asub[kk][ty * 4];
            #pragma unroll
            for (int cb = 0; cb < 4; ++cb) {
                float4 b4 = *(const float4*)&Bsub[kk][cb * 64 + tx * 4];
                acc[cb][0][0] += a4.x * b4.x; acc[cb][0][1] += a4.x * b4.y; acc[cb][0][2] += a4.x * b4.z; acc[cb][0][3] += a4.x * b4.w;
                acc[cb][1][0] += a4.y * b4.x; acc[cb][1][1] += a4.y * b4.y; acc[cb][1][2] += a4.y * b4.z; acc[cb][1][3] += a4.y * b4.w;
                acc[cb][2][0] += a4.z * b4.x; acc[cb][2][1] += a4.z * b4.y; acc[cb][2][2] += a4.z * b4.z; acc[cb][2][3] += a4.z * b4.w;
                acc[cb][3][0] += a4.w * b4.x; acc[cb][3][1] += a4.w * b4.y; acc[cb][3][2] += a4.w * b4.z; acc[cb][3][3] += a4.w * b4.w;
            }
        }
        __syncthreads();
    }
    #pragma unroll
    for (int cb = 0; cb < 4; ++cb) {
        const int cg = cb * 64 + tx * 4;
        const int h = cg >> 5, e = cg & 31;
        if (p == vt_p) {
            // V^T: Op[((h*16+b)*32 + e+j)*NR + n]
            #pragma unroll
            for (int i = 0; i < 4; ++i) {
                int n = n0 + ty * 4 + i;
                #pragma unroll
                for (int j = 0; j < 4; ++j)
                    Op[(((size_t)h * 16 + b) * 32 + e + j) * rows_per_b + n] = (f16)acc[cb][i][j];
            }
        } else {
            #pragma unroll
            for (int i = 0; i < 4; ++i) {
                int n = n0 + ty * 4 + i;
                f16x4 v = { (f16)acc[cb][i][0], (f16)acc[cb][i][1], (f16)acc[cb][i][2], (f16)acc[cb][i][3] };
                *(f16x4*)&Op[(((size_t)h * 16 + b) * rows_per_b + n) * 32 + e] = v;
            }
        }
    }
}

// ---------------------------------------------------------------------------
// Output projection: C[bq][d] = HEADS[8192,256] @ W_out[256,256]  (fp32)
// R6: merged column-quadrants — one block computes 64x256 (see proj_gemm).
// ---------------------------------------------------------------------------
__global__ __launch_bounds__(256)
void out_gemm(const float* __restrict__ A, const float* __restrict__ Bm,
              float* __restrict__ C)
{
    __shared__ float Asub[32][68];
    __shared__ float Bsub[32][256];
    const int tid = (int)threadIdx.x;
    const int row0 = (int)blockIdx.x * 64;
    const int tx = tid & 15, ty = tid >> 4;
    float acc[4][4][4] = {};                 // [cb][row i][col j]

    for (int k0 = 0; k0 < 256; k0 += 32) {
        #pragma unroll
        for (int i = 0; i < 8; ++i) {
            int idx = tid + 256 * i;
            int kk = idx & 31, r = idx >> 5;
            Asub[kk][r] = A[(size_t)(row0 + r) * 256 + k0 + kk];
        }
        {
            const float* bb = Bm + (size_t)k0 * 256 + tid;
            #pragma unroll
            for (int kk = 0; kk < 32; ++kk)
                Bsub[kk][tid] = bb[kk * 256];
        }
        __syncthreads();
        #pragma unroll 4
        for (int kk = 0; kk < 32; ++kk) {
            float4 a4 = *(const float4*)&Asub[kk][ty * 4];
            #pragma unroll
            for (int cb = 0; cb < 4; ++cb) {
                float4 b4 = *(const float4*)&Bsub[kk][cb * 64 + tx * 4];
                acc[cb][0][0] += a4.x * b4.x; acc[cb][0][1] += a4.x * b4.y; acc[cb][0][2] += a4.x * b4.z; acc[cb][0][3] += a4.x * b4.w;
                acc[cb][1][0] += a4.y * b4.x; acc[cb][1][1] += a4.y * b4.y; acc[cb][1][2] += a4.y * b4.z; acc[cb][1][3] += a4.y * b4.w;
                acc[cb][2][0] += a4.z * b4.x; acc[cb][2][1] += a4.z * b4.y; acc[cb][2][2] += a4.z * b4.z; acc[cb][2][3] += a4.z * b4.w;
                acc[cb][3][0] += a4.w * b4.x; acc[cb][3][1] += a4.w * b4.y; acc[cb][3][2] += a4.w * b4.z; acc[cb][3][3] += a4.w * b4.w;
            }
        }
        __syncthreads();
    }
    #pragma unroll
    for (int cb = 0; cb < 4; ++cb) {
        #pragma unroll
        for (int i = 0; i < 4; ++i) {
            float4 v = make_float4(acc[cb][i][0], acc[cb][i][1], acc[cb][i][2], acc[cb][i][3]);
            *(float4*)&C[(size_t)(row0 + ty * 4 + i) * 256 + cb * 64 + tx * 4] = v;
        }
    }
}

// ---------------------------------------------------------------------------
// MFMA attend partial.  512 threads / 8 waves.  16 query rows x 32 keys per
// step, 8 heads.  Wave w owns head w (one head per wave).  K: [h][b][m][32]
// f16.  V^T: [h][b][e][ML] f16.  Scores + P@V via mfma 16x16x32 f16.
// MLP role: 1 position per thread (mn=tid>>5 row, mi=tid&31 key).
// R5 verified: VGPR=56, occupancy 39-40%, no spill, 137us big dispatch.
// M/L online-softmax state lives in LDS (MLs); each MLs row is private to
// one 32-lane group (read-broadcast, written by lane mi==0 after the rsum
// shuffle-reduce that transitively depends on all lanes' reads -> race-free).
// ---------------------------------------------------------------------------
__global__ __launch_bounds__(512)
void attend_mfma(const f16* __restrict__ Qb, const f16* __restrict__ Kb,
                 const f16* __restrict__ Vt, const float* __restrict__ aux,
                 const float* __restrict__ W1g, const float* __restrict__ b1g,
                 const float* __restrict__ W2g, const float* __restrict__ b2g,
                 f16* __restrict__ o_part, float* __restrict__ ml_part,
                 int NR, int ML, int KCHUNK, int n_off, int m_off)
{
    __shared__ float Sx[16 * 289];       // [n]*289 + m*9 + h   (m 0..31, h 0..7)
    __shared__ f16   Pb[8 * 16 * 32];    // [h][n][m] f16 (A-frag friendly)
    __shared__ float Wl[408];            // W1(256) | W2(128) | b1(16) | b2(8)
    __shared__ float Alph[128];          // [n][h]
    __shared__ float MLs[256];           // [n][h][{M,L}]

    const int tid   = (int)threadIdx.x;
    const int n0g   = (int)blockIdx.x * 16;
    const int b     = (int)blockIdx.y;
    const int chunk = (int)blockIdx.z;
    const int m_base = chunk * KCHUNK;

    if (tid < 256) Wl[tid] = W1g[tid];
    if (tid >= 256 && tid < 384) Wl[tid] = W2g[tid - 256];
    if (tid >= 384 && tid < 400) Wl[tid] = b1g[tid - 384];
    if (tid >= 400 && tid < 408) Wl[tid] = b2g[tid - 400];
    if (tid < 128) { MLs[tid * 2] = -INFINITY; MLs[tid * 2 + 1] = 0.f; }

    const int lane = tid & 63, ln = lane & 15, qd = lane >> 4;
    const int wid  = tid >> 6;           // head owned by this wave (0..7)
    // MLP role: row n0g+mn, key mi within the 32-key step
    const int mn = tid >> 5, mi = tid & 31;

    // Q fragment (A-layout: row=ln, k=qd*8..qd*8+7), resident all steps
    f16x8 qf = *(const f16x8*)(Qb + ((((size_t)wid * 16 + b) * NR + n0g + ln) * 32) + qd * 8);

    f32x4 oacc[2];
    oacc[0] = (f32x4){0.f, 0.f, 0.f, 0.f};
    oacc[1] = (f32x4){0.f, 0.f, 0.f, 0.f};

    // aux prefetch for first step (coalesced: consecutive mi -> consecutive m)
    const size_t aux_row = ((size_t)b * 512 + (n_off + n0g + mn)) * 512 + m_off;
    float auxr[8];
    #pragma unroll
    for (int h = 0; h < 8; ++h)
        auxr[h] = aux[(size_t)h * 16 * 512 * 512 + aux_row + m_base + mi];
    __syncthreads();

    for (int m0 = m_base; m0 < m_base + KCHUNK; m0 += 32) {
        // ---- phase A: scores via MFMA, scatter C-frags to Sx ----
        #pragma unroll
        for (int mt = 0; mt < 2; ++mt) {
            f16x8 kf = *(const f16x8*)(Kb + ((((size_t)wid * 16 + b) * ML + m0 + mt * 16 + ln) * 32) + qd * 8);
            f32x4 c = __builtin_amdgcn_mfma_f32_16x16x32_f16(qf, kf, (f32x4){0.f,0.f,0.f,0.f}, 0, 0, 0);
            #pragma unroll
            for (int r = 0; r < 4; ++r)
                Sx[(qd * 4 + r) * 289 + (mt * 16 + ln) * 9 + wid] = c[r];
        }
        __syncthreads();

        // ---- phase B: fused MLP (1 position/thread) + online softmax ----
        {
            float Mold[8];
            #pragma unroll
            for (int h = 0; h < 8; ++h) Mold[h] = MLs[(mn * 8 + h) * 2];

            float x[16];
            #pragma unroll
            for (int h = 0; h < 8; ++h) {
                x[h]     = Sx[mn * 289 + mi * 9 + h];
                x[8 + h] = auxr[h];
            }
            float hid[16];
            #pragma unroll
            for (int j = 0; j < 16; ++j) hid[j] = Wl[384 + j];
            #pragma unroll
            for (int i = 0; i < 16; ++i) {
                const float a = x[i];
                #pragma unroll
                for (int j = 0; j < 16; ++j) hid[j] += a * Wl[i * 16 + j];
            }
            float f[8];
            #pragma unroll
            for (int o = 0; o < 8; ++o) f[o] = Wl[400 + o];
            #pragma unroll
            for (int j = 0; j < 16; ++j) {
                const float g = fmaxf(hid[j], 0.f);
                #pragma unroll
                for (int o = 0; o < 8; ++o) f[o] += g * Wl[256 + j * 8 + o];
            }
            // softmax over the 32 m (one per lane of the 32-lane group)
            float rmax[8];
            #pragma unroll
            for (int h = 0; h < 8; ++h) rmax[h] = f[h];
            #pragma unroll
            for (int d = 1; d < 32; d <<= 1)
                #pragma unroll
                for (int h = 0; h < 8; ++h) rmax[h] = fmaxf(rmax[h], __shfl_xor(rmax[h], d));
            float alr[8], rsum[8];
            #pragma unroll
            for (int h = 0; h < 8; ++h) {
                const float nM = fmaxf(Mold[h], rmax[h]);
                alr[h] = __expf(Mold[h] - nM);
                const float e = __expf(f[h] - nM);
                f[h] = e;
                rsum[h] = e;
            }
            #pragma unroll
            for (int d = 1; d < 32; d <<= 1)
                #pragma unroll
                for (int h = 0; h < 8; ++h) rsum[h] += __shfl_xor(rsum[h], d);
            #pragma unroll
            for (int h = 0; h < 8; ++h)
                Pb[((size_t)h * 16 + mn) * 32 + mi] = (f16)f[h];
            // M/L update + alpha publish: ordered after the rsum reduce (which
            // transitively depends on every lane's Mold read -> no read race)
            if (mi == 0) {
                #pragma unroll
                for (int h = 0; h < 8; ++h) {
                    const int ix = (mn * 8 + h) * 2;
                    const float nM = fmaxf(Mold[h], rmax[h]);
                    const float Lold = MLs[ix + 1];
                    MLs[ix]     = nM;
                    MLs[ix + 1] = Lold * alr[h] + rsum[h];
                    Alph[mn * 8 + h] = alr[h];
                }
            }
            // prefetch aux for next step (consumed after 2 barriers)
            if (m0 + 32 < m_base + KCHUNK) {
                #pragma unroll
                for (int h = 0; h < 8; ++h)
                    auxr[h] = aux[(size_t)h * 16 * 512 * 512 + aux_row + m0 + 32 + mi];
            }
        }
        __syncthreads();

        // ---- phase C: rescale accumulator, P @ V via MFMA ----
        {
            float al[4];
            #pragma unroll
            for (int r = 0; r < 4; ++r) al[r] = Alph[(qd * 4 + r) * 8 + wid];
            f16x8 pf = *(const f16x8*)&Pb[((size_t)wid * 16 + ln) * 32 + qd * 8];
            #pragma unroll
            for (int hf = 0; hf < 2; ++hf) {
                f16x8 vf = *(const f16x8*)(Vt + ((((size_t)wid * 16 + b) * 32 + hf * 16 + ln) * ML) + m0 + qd * 8);
                f32x4 c = oacc[hf];
                #pragma unroll
                for (int r = 0; r < 4; ++r) c[r] *= al[r];
                oacc[hf] = __builtin_amdgcn_mfma_f32_16x16x32_f16(pf, vf, c, 0, 0, 0);
            }
        }
    }

    // ---- epilogue: unnormalized o (f16), (m,l) fp32 ----
    #pragma unroll
    for (int hf = 0; hf < 2; ++hf)
        #pragma unroll
        for (int r = 0; r < 4; ++r)
            o_part[(((((size_t)chunk * 8 + wid) * 16 + b) * NR + n0g + qd * 4 + r) * 32) + hf * 16 + ln]
                = (f16)oacc[hf][r];
    if (mi == 0) {
        #pragma unroll
        for (int h = 0; h < 8; ++h) {
            const size_t base = ((((size_t)chunk * 8 + h) * 16 + b) * NR + n0g + mn) * 2;
            ml_part[base]     = MLs[(mn * 8 + h) * 2];
            ml_part[base + 1] = MLs[(mn * 8 + h) * 2 + 1];
        }
    }
}

// ---------------------------------------------------------------------------
// Combine: merge nchA key-chunks (shared softmax) + optional group-B partial
// (independent softmax, added). Writes HE[b][q_off+n][h*32+e] fp32.
// ---------------------------------------------------------------------------
__global__ __launch_bounds__(256)
void combine_kernel(const f16* __restrict__ oA, const float* __restrict__ mlA, int nchA,
                    const f16* __restrict__ oB, const float* __restrict__ mlB,
                    float* __restrict__ HE, int NR, int q_off)
{
    const int tid = (int)threadIdx.x;
    const int sn = tid >> 4, sh = (tid >> 1) & 7, smh = tid & 1;
    const int n = (int)blockIdx.x * 16 + sn;
    const int b = (int)blockIdx.y;

    float M = -INFINITY;
    for (int c = 0; c < nchA; ++c)
        M = fmaxf(M, mlA[((((size_t)c * 8 + sh) * 16 + b) * NR + n) * 2]);
    float L = 0.f;
    float o[16];
    #pragma unroll
    for (int j = 0; j < 16; ++j) o[j] = 0.f;
    for (int c = 0; c < nchA; ++c) {
        const size_t mlb = ((((size_t)c * 8 + sh) * 16 + b) * NR + n) * 2;
        const float w = __expf(mlA[mlb] - M);
        L += mlA[mlb + 1] * w;
        const f16* src = oA + ((((size_t)c * 8 + sh) * 16 + b) * NR + n) * 32 + smh * 16;
        #pragma unroll
        for (int j = 0; j < 16; ++j) o[j] += w * (float)src[j];
    }
    const float invL = 1.f / L;
    #pragma unroll
    for (int j = 0; j < 16; ++j) o[j] *= invL;

    if (oB != nullptr) {
        const float invB = 1.f / mlB[(((size_t)sh * 16 + b) * NR + n) * 2 + 1];
        const f16* src = oB + (((size_t)sh * 16 + b) * NR + n) * 32 + smh * 16;
        #pragma unroll
        for (int j = 0; j < 16; ++j) o[j] += invB * (float)src[j];
    }
    float* dst = HE + ((size_t)b * 512 + q_off + n) * 256 + sh * 32 + smh * 16;
    #pragma unroll
    for (int j4 = 0; j4 < 4; ++j4)
        *(float4*)(dst + j4 * 4) = make_float4(o[j4*4+0], o[j4*4+1], o[j4*4+2], o[j4*4+3]);
}

// ---------------------------------------------------------------------------
extern "C" void kernel_launch(void* const* d_in, const int* in_sizes, int n_in,
                              void* d_out, int out_size, void* d_ws, size_t ws_size,
                              hipStream_t stream)
{
    (void)in_sizes; (void)n_in; (void)out_size; (void)ws_size;

    const float* h_fea  = (const float*)d_in[0];
    const float* aux    = (const float*)d_in[1];
    const float* Wq_c   = (const float*)d_in[2];
    const float* Wq_c1  = (const float*)d_in[3];
    const float* Wk_c   = (const float*)d_in[4];
    const float* Wv_c   = (const float*)d_in[5];
    const float* Wq_ch1 = (const float*)d_in[6];
    const float* Wk_ch  = (const float*)d_in[7];
    const float* Wv_ch  = (const float*)d_in[8];
    const float* W1     = (const float*)d_in[9];
    const float* b1     = (const float*)d_in[10];
    const float* W2     = (const float*)d_in[11];
    const float* b2     = (const float*)d_in[12];
    const float* W_out  = (const float*)d_in[13];

    const size_t TBIG = (size_t)8 * 16 * 448 * 32;   // 1,835,008 elems
    const size_t TSML = (size_t)8 * 16 * 64 * 32;    //   262,144 elems
    char* wp = (char*)d_ws;
    auto alloc = [&](size_t bytes) { char* p = wp; wp += (bytes + 255) & ~(size_t)255; return p; };

    f16*   QT1 = (f16*)alloc(TBIG * 2);
    f16*   QT  = (f16*)alloc(TBIG * 2);
    f16*   KC  = (f16*)alloc(TBIG * 2);
    f16*   VCT = (f16*)alloc(TBIG * 2);              // V_c transposed [h][b][e][448]
    f16*   QS  = (f16*)alloc(TSML * 2);
    f16*   KS  = (f16*)alloc(TSML * 2);
    f16*   VST = (f16*)alloc(TSML * 2);              // V_s transposed [h][b][e][64]
    float* HE  = (float*)alloc((size_t)16 * 512 * 256 * 4);
    f16*   oA  = (f16*)alloc(7 * TBIG * 2);
    float* mlA = (float*)alloc((size_t)7 * 8 * 16 * 448 * 2 * 4);
    f16*   oB  = (f16*)alloc(TBIG * 2);
    float* mlB = (float*)alloc((size_t)8 * 16 * 448 * 2 * 4);
    f16*   oC  = (f16*)alloc(7 * TSML * 2);
    float* mlC = (float*)alloc((size_t)7 * 8 * 16 * 64 * 2 * 4);

    // Projections (task rows q 64..511, stat rows q 0..63); V outputs transposed
    // R6: blockIdx.y = projection index only (columns merged into the block)
    proj_gemm<<<dim3(112, 4), 256, 0, stream>>>(h_fea, Wq_c1, Wq_c, Wk_c, Wv_c,
                                                QT1, QT, KC, VCT, 64, 448, 7, 3);
    proj_gemm<<<dim3(16, 3), 256, 0, stream>>>(h_fea, Wq_ch1, Wk_ch, Wv_ch, Wv_ch,
                                               QS, KS, VST, VST, 0, 64, 1, 2);

    // attend1: task q vs task k (448 keys, 7 chunks of 64)
    attend_mfma<<<dim3(28, 16, 7), 512, 0, stream>>>(QT1, KC, VCT, aux, W1, b1, W2, b2,
                                                     oA, mlA, 448, 448, 64, 64, 64);
    // attend2: task q vs stat k (64 keys, 1 chunk)
    attend_mfma<<<dim3(28, 16, 1), 512, 0, stream>>>(QT, KS, VST, aux, W1, b1, W2, b2,
                                                     oB, mlB, 448, 64, 64, 64, 0);
    // attend3: stat q vs task k (448 keys, 7 chunks of 64)
    attend_mfma<<<dim3(4, 16, 7), 512, 0, stream>>>(QS, KC, VCT, aux, W1, b1, W2, b2,
                                                    oC, mlC, 64, 448, 64, 0, 64);

    // Combine
    combine_kernel<<<dim3(28, 16), 256, 0, stream>>>(oA, mlA, 7, oB, mlB, HE, 448, 64);
    combine_kernel<<<dim3(4, 16), 256, 0, stream>>>(oC, mlC, 7, nullptr, nullptr, HE, 64, 0);

    // h_wave = HEADS[8192,256] @ W_out[256,256]
    out_gemm<<<dim3(128), 256, 0, stream>>>(HE, W_out, (float*)d_out);
}

// Round 7
// 492.004 us; speedup vs baseline: 1.0896x; 1.0896x over previous
//
#include <hip/hip_runtime.h>
#include <math.h>

// Shapes (fixed): H=8, D=256, HD=32, B=16, Q=512, S1=64, NTASK=448
typedef _Float16 f16;
typedef f16  f16x8 __attribute__((ext_vector_type(8)));
typedef f16  f16x4 __attribute__((ext_vector_type(4)));
typedef f16  f16x2 __attribute__((ext_vector_type(2)));
typedef float f32x4 __attribute__((ext_vector_type(4)));

// ---------------------------------------------------------------------------
// Projection GEMM (fp32 compute, fp16 output), 64-row x 128-col tiles.
// R7 tile-size history: R5 64x64 (1792 blocks, 16 FMA : 2 LDS reads/kk,
// ~190us) -> R6 64x256 (448 blocks: 4x density but grid-starved on 256 CUs,
// REGRESSED) -> R7 64x128 (896 blocks = 3.5/CU, 32 FMA : 3 LDS reads/kk).
// blockIdx.y = p*2 + colhalf.  Accumulation order per output unchanged
// vs R5/R6 -> bitwise-identical results.
// Normal outputs: [h][b][n][32] fp16 row-major.  V output (p==vt_p): V^T
// layout [h][b][e][NR] fp16 (contiguous m) for MFMA B-fragments.
// ---------------------------------------------------------------------------
__global__ __launch_bounds__(256)
void proj_gemm(const float* __restrict__ A,
               const float* __restrict__ W0, const float* __restrict__ W1p,
               const float* __restrict__ W2p, const float* __restrict__ W3p,
               f16* __restrict__ O0, f16* __restrict__ O1,
               f16* __restrict__ O2, f16* __restrict__ O3,
               int q_off, int rows_per_b, int tiles_per_b, int vt_p)
{
    __shared__ float Asub[32][68];
    __shared__ float Bsub[32][128];
    const int tid = (int)threadIdx.x;
    const int b  = (int)blockIdx.x / tiles_per_b;
    const int n0 = ((int)blockIdx.x % tiles_per_b) * 64;
    const int p  = (int)blockIdx.y >> 1;
    const int c0 = ((int)blockIdx.y & 1) * 128;
    const float* Wp = (p == 0) ? W0 : (p == 1) ? W1p : (p == 2) ? W2p : W3p;
    f16* Op         = (p == 0) ? O0 : (p == 1) ? O1 : (p == 2) ? O2 : O3;

    const int tx = tid & 15, ty = tid >> 4;
    float acc[2][4][4] = {};                 // [cb][row i][col j] -> registers
    const float* Arow = A + (size_t)(b * 512 + q_off + n0) * 256;

    for (int k0 = 0; k0 < 256; k0 += 32) {
        #pragma unroll
        for (int i = 0; i < 8; ++i) {
            int idx = tid + 256 * i;
            int kk = idx & 31, r = idx >> 5;
            Asub[kk][r] = Arow[(size_t)r * 256 + k0 + kk];
        }
        #pragma unroll
        for (int i = 0; i < 16; ++i) {
            int idx = tid + 256 * i;
            int c = idx & 127, kk = idx >> 7;
            int cg = c0 + c;
            int h = cg >> 5, e = cg & 31;
            Bsub[kk][c] = Wp[(size_t)(h * 256 + k0 + kk) * 32 + e];
        }
        __syncthreads();
        #pragma unroll 4
        for (int kk = 0; kk < 32; ++kk) {
            float4 a4 = *(const float4*)&Asub[kk][ty * 4];
            #pragma unroll
            for (int cb = 0; cb < 2; ++cb) {
                float4 b4 = *(const float4*)&Bsub[kk][cb * 64 + tx * 4];
                acc[cb][0][0] += a4.x * b4.x; acc[cb][0][1] += a4.x * b4.y; acc[cb][0][2] += a4.x * b4.z; acc[cb][0][3] += a4.x * b4.w;
                acc[cb][1][0] += a4.y * b4.x; acc[cb][1][1] += a4.y * b4.y; acc[cb][1][2] += a4.y * b4.z; acc[cb][1][3] += a4.y * b4.w;
                acc[cb][2][0] += a4.z * b4.x; acc[cb][2][1] += a4.z * b4.y; acc[cb][2][2] += a4.z * b4.z; acc[cb][2][3] += a4.z * b4.w;
                acc[cb][3][0] += a4.w * b4.x; acc[cb][3][1] += a4.w * b4.y; acc[cb][3][2] += a4.w * b4.z; acc[cb][3][3] += a4.w * b4.w;
            }
        }
        __syncthreads();
    }
    #pragma unroll
    for (int cb = 0; cb < 2; ++cb) {
        const int cg = c0 + cb * 64 + tx * 4;
        const int h = cg >> 5, e = cg & 31;
        if (p == vt_p) {
            // V^T: Op[((h*16+b)*32 + e+j)*NR + n]
            #pragma unroll
            for (int i = 0; i < 4; ++i) {
                int n = n0 + ty * 4 + i;
                #pragma unroll
                for (int j = 0; j < 4; ++j)
                    Op[(((size_t)h * 16 + b) * 32 + e + j) * rows_per_b + n] = (f16)acc[cb][i][j];
            }
        } else {
            #pragma unroll
            for (int i = 0; i < 4; ++i) {
                int n = n0 + ty * 4 + i;
                f16x4 v = { (f16)acc[cb][i][0], (f16)acc[cb][i][1], (f16)acc[cb][i][2], (f16)acc[cb][i][3] };
                *(f16x4*)&Op[(((size_t)h * 16 + b) * rows_per_b + n) * 32 + e] = v;
            }
        }
    }
}

// ---------------------------------------------------------------------------
// Output projection: C[bq][d] = HEADS[8192,256] @ W_out[256,256]  (fp32)
// R7: 64x128 tiles, grid (128,2)=256 blocks (R6's 64x256 at 128 blocks left
// half the CUs idle).
// ---------------------------------------------------------------------------
__global__ __launch_bounds__(256)
void out_gemm(const float* __restrict__ A, const float* __restrict__ Bm,
              float* __restrict__ C)
{
    __shared__ float Asub[32][68];
    __shared__ float Bsub[32][128];
    const int tid = (int)threadIdx.x;
    const int row0 = (int)blockIdx.x * 64;
    const int col0 = (int)blockIdx.y * 128;
    const int tx = tid & 15, ty = tid >> 4;
    float acc[2][4][4] = {};                 // [cb][row i][col j]

    for (int k0 = 0; k0 < 256; k0 += 32) {
        #pragma unroll
        for (int i = 0; i < 8; ++i) {
            int idx = tid + 256 * i;
            int kk = idx & 31, r = idx >> 5;
            Asub[kk][r] = A[(size_t)(row0 + r) * 256 + k0 + kk];
        }
        #pragma unroll
        for (int i = 0; i < 16; ++i) {
            int idx = tid + 256 * i;
            int c = idx & 127, kk = idx >> 7;
            Bsub[kk][c] = Bm[(size_t)(k0 + kk) * 256 + col0 + c];
        }
        __syncthreads();
        #pragma unroll 4
        for (int kk = 0; kk < 32; ++kk) {
            float4 a4 = *(const float4*)&Asub[kk][ty * 4];
            #pragma unroll
            for (int cb = 0; cb < 2; ++cb) {
                float4 b4 = *(const float4*)&Bsub[kk][cb * 64 + tx * 4];
                acc[cb][0][0] += a4.x * b4.x; acc[cb][0][1] += a4.x * b4.y; acc[cb][0][2] += a4.x * b4.z; acc[cb][0][3] += a4.x * b4.w;
                acc[cb][1][0] += a4.y * b4.x; acc[cb][1][1] += a4.y * b4.y; acc[cb][1][2] += a4.y * b4.z; acc[cb][1][3] += a4.y * b4.w;
                acc[cb][2][0] += a4.z * b4.x; acc[cb][2][1] += a4.z * b4.y; acc[cb][2][2] += a4.z * b4.z; acc[cb][2][3] += a4.z * b4.w;
                acc[cb][3][0] += a4.w * b4.x; acc[cb][3][1] += a4.w * b4.y; acc[cb][3][2] += a4.w * b4.z; acc[cb][3][3] += a4.w * b4.w;
            }
        }
        __syncthreads();
    }
    #pragma unroll
    for (int cb = 0; cb < 2; ++cb) {
        #pragma unroll
        for (int i = 0; i < 4; ++i) {
            float4 v = make_float4(acc[cb][i][0], acc[cb][i][1], acc[cb][i][2], acc[cb][i][3]);
            *(float4*)&C[(size_t)(row0 + ty * 4 + i) * 256 + col0 + cb * 64 + tx * 4] = v;
        }
    }
}

// ---------------------------------------------------------------------------
// MFMA attend partial.  512 threads / 8 waves.  16 query rows x 32 keys per
// step, 8 heads.  Wave w owns head w (one head per wave).  K: [h][b][m][32]
// f16.  V^T: [h][b][e][ML] f16.  Scores + P@V via mfma 16x16x32 f16.
// MLP role: 1 position per thread (mn=tid>>5 row, mi=tid&31 key).
// R5 verified: VGPR=56, occupancy 39-40%, no spill, 137us big dispatch.
// M/L online-softmax state lives in LDS (MLs); each MLs row is private to
// one 32-lane group (read-broadcast, written by lane mi==0 after the rsum
// shuffle-reduce that transitively depends on all lanes' reads -> race-free).
// ---------------------------------------------------------------------------
__global__ __launch_bounds__(512)
void attend_mfma(const f16* __restrict__ Qb, const f16* __restrict__ Kb,
                 const f16* __restrict__ Vt, const float* __restrict__ aux,
                 const float* __restrict__ W1g, const float* __restrict__ b1g,
                 const float* __restrict__ W2g, const float* __restrict__ b2g,
                 f16* __restrict__ o_part, float* __restrict__ ml_part,
                 int NR, int ML, int KCHUNK, int n_off, int m_off)
{
    __shared__ float Sx[16 * 289];       // [n]*289 + m*9 + h   (m 0..31, h 0..7)
    __shared__ f16   Pb[8 * 16 * 32];    // [h][n][m] f16 (A-frag friendly)
    __shared__ float Wl[408];            // W1(256) | W2(128) | b1(16) | b2(8)
    __shared__ float Alph[128];          // [n][h]
    __shared__ float MLs[256];           // [n][h][{M,L}]

    const int tid   = (int)threadIdx.x;
    const int n0g   = (int)blockIdx.x * 16;
    const int b     = (int)blockIdx.y;
    const int chunk = (int)blockIdx.z;
    const int m_base = chunk * KCHUNK;

    if (tid < 256) Wl[tid] = W1g[tid];
    if (tid >= 256 && tid < 384) Wl[tid] = W2g[tid - 256];
    if (tid >= 384 && tid < 400) Wl[tid] = b1g[tid - 384];
    if (tid >= 400 && tid < 408) Wl[tid] = b2g[tid - 400];
    if (tid < 128) { MLs[tid * 2] = -INFINITY; MLs[tid * 2 + 1] = 0.f; }

    const int lane = tid & 63, ln = lane & 15, qd = lane >> 4;
    const int wid  = tid >> 6;           // head owned by this wave (0..7)
    // MLP role: row n0g+mn, key mi within the 32-key step
    const int mn = tid >> 5, mi = tid & 31;

    // Q fragment (A-layout: row=ln, k=qd*8..qd*8+7), resident all steps
    f16x8 qf = *(const f16x8*)(Qb + ((((size_t)wid * 16 + b) * NR + n0g + ln) * 32) + qd * 8);

    f32x4 oacc[2];
    oacc[0] = (f32x4){0.f, 0.f, 0.f, 0.f};
    oacc[1] = (f32x4){0.f, 0.f, 0.f, 0.f};

    // aux prefetch for first step (coalesced: consecutive mi -> consecutive m)
    const size_t aux_row = ((size_t)b * 512 + (n_off + n0g + mn)) * 512 + m_off;
    float auxr[8];
    #pragma unroll
    for (int h = 0; h < 8; ++h)
        auxr[h] = aux[(size_t)h * 16 * 512 * 512 + aux_row + m_base + mi];
    __syncthreads();

    for (int m0 = m_base; m0 < m_base + KCHUNK; m0 += 32) {
        // ---- phase A: scores via MFMA, scatter C-frags to Sx ----
        #pragma unroll
        for (int mt = 0; mt < 2; ++mt) {
            f16x8 kf = *(const f16x8*)(Kb + ((((size_t)wid * 16 + b) * ML + m0 + mt * 16 + ln) * 32) + qd * 8);
            f32x4 c = __builtin_amdgcn_mfma_f32_16x16x32_f16(qf, kf, (f32x4){0.f,0.f,0.f,0.f}, 0, 0, 0);
            #pragma unroll
            for (int r = 0; r < 4; ++r)
                Sx[(qd * 4 + r) * 289 + (mt * 16 + ln) * 9 + wid] = c[r];
        }
        __syncthreads();

        // ---- phase B: fused MLP (1 position/thread) + online softmax ----
        {
            float Mold[8];
            #pragma unroll
            for (int h = 0; h < 8; ++h) Mold[h] = MLs[(mn * 8 + h) * 2];

            float x[16];
            #pragma unroll
            for (int h = 0; h < 8; ++h) {
                x[h]     = Sx[mn * 289 + mi * 9 + h];
                x[8 + h] = auxr[h];
            }
            float hid[16];
            #pragma unroll
            for (int j = 0; j < 16; ++j) hid[j] = Wl[384 + j];
            #pragma unroll
            for (int i = 0; i < 16; ++i) {
                const float a = x[i];
                #pragma unroll
                for (int j = 0; j < 16; ++j) hid[j] += a * Wl[i * 16 + j];
            }
            float f[8];
            #pragma unroll
            for (int o = 0; o < 8; ++o) f[o] = Wl[400 + o];
            #pragma unroll
            for (int j = 0; j < 16; ++j) {
                const float g = fmaxf(hid[j], 0.f);
                #pragma unroll
                for (int o = 0; o < 8; ++o) f[o] += g * Wl[256 + j * 8 + o];
            }
            // softmax over the 32 m (one per lane of the 32-lane group)
            float rmax[8];
            #pragma unroll
            for (int h = 0; h < 8; ++h) rmax[h] = f[h];
            #pragma unroll
            for (int d = 1; d < 32; d <<= 1)
                #pragma unroll
                for (int h = 0; h < 8; ++h) rmax[h] = fmaxf(rmax[h], __shfl_xor(rmax[h], d));
            float alr[8], rsum[8];
            #pragma unroll
            for (int h = 0; h < 8; ++h) {
                const float nM = fmaxf(Mold[h], rmax[h]);
                alr[h] = __expf(Mold[h] - nM);
                const float e = __expf(f[h] - nM);
                f[h] = e;
                rsum[h] = e;
            }
            #pragma unroll
            for (int d = 1; d < 32; d <<= 1)
                #pragma unroll
                for (int h = 0; h < 8; ++h) rsum[h] += __shfl_xor(rsum[h], d);
            #pragma unroll
            for (int h = 0; h < 8; ++h)
                Pb[((size_t)h * 16 + mn) * 32 + mi] = (f16)f[h];
            // M/L update + alpha publish: ordered after the rsum reduce (which
            // transitively depends on every lane's Mold read -> no read race)
            if (mi == 0) {
                #pragma unroll
                for (int h = 0; h < 8; ++h) {
                    const int ix = (mn * 8 + h) * 2;
                    const float nM = fmaxf(Mold[h], rmax[h]);
                    const float Lold = MLs[ix + 1];
                    MLs[ix]     = nM;
                    MLs[ix + 1] = Lold * alr[h] + rsum[h];
                    Alph[mn * 8 + h] = alr[h];
                }
            }
            // prefetch aux for next step (consumed after 2 barriers)
            if (m0 + 32 < m_base + KCHUNK) {
                #pragma unroll
                for (int h = 0; h < 8; ++h)
                    auxr[h] = aux[(size_t)h * 16 * 512 * 512 + aux_row + m0 + 32 + mi];
            }
        }
        __syncthreads();

        // ---- phase C: rescale accumulator, P @ V via MFMA ----
        {
            float al[4];
            #pragma unroll
            for (int r = 0; r < 4; ++r) al[r] = Alph[(qd * 4 + r) * 8 + wid];
            f16x8 pf = *(const f16x8*)&Pb[((size_t)wid * 16 + ln) * 32 + qd * 8];
            #pragma unroll
            for (int hf = 0; hf < 2; ++hf) {
                f16x8 vf = *(const f16x8*)(Vt + ((((size_t)wid * 16 + b) * 32 + hf * 16 + ln) * ML) + m0 + qd * 8);
                f32x4 c = oacc[hf];
                #pragma unroll
                for (int r = 0; r < 4; ++r) c[r] *= al[r];
                oacc[hf] = __builtin_amdgcn_mfma_f32_16x16x32_f16(pf, vf, c, 0, 0, 0);
            }
        }
    }

    // ---- epilogue: unnormalized o (f16), (m,l) fp32 ----
    #pragma unroll
    for (int hf = 0; hf < 2; ++hf)
        #pragma unroll
        for (int r = 0; r < 4; ++r)
            o_part[(((((size_t)chunk * 8 + wid) * 16 + b) * NR + n0g + qd * 4 + r) * 32) + hf * 16 + ln]
                = (f16)oacc[hf][r];
    if (mi == 0) {
        #pragma unroll
        for (int h = 0; h < 8; ++h) {
            const size_t base = ((((size_t)chunk * 8 + h) * 16 + b) * NR + n0g + mn) * 2;
            ml_part[base]     = MLs[(mn * 8 + h) * 2];
            ml_part[base + 1] = MLs[(mn * 8 + h) * 2 + 1];
        }
    }
}

// ---------------------------------------------------------------------------
// Combine: merge nchA key-chunks (shared softmax) + optional group-B partial
// (independent softmax, added). Writes HE[b][q_off+n][h*32+e] fp32.
// ---------------------------------------------------------------------------
__global__ __launch_bounds__(256)
void combine_kernel(const f16* __restrict__ oA, const float* __restrict__ mlA, int nchA,
                    const f16* __restrict__ oB, const float* __restrict__ mlB,
                    float* __restrict__ HE, int NR, int q_off)
{
    const int tid = (int)threadIdx.x;
    const int sn = tid >> 4, sh = (tid >> 1) & 7, smh = tid & 1;
    const int n = (int)blockIdx.x * 16 + sn;
    const int b = (int)blockIdx.y;

    float M = -INFINITY;
    for (int c = 0; c < nchA; ++c)
        M = fmaxf(M, mlA[((((size_t)c * 8 + sh) * 16 + b) * NR + n) * 2]);
    float L = 0.f;
    float o[16];
    #pragma unroll
    for (int j = 0; j < 16; ++j) o[j] = 0.f;
    for (int c = 0; c < nchA; ++c) {
        const size_t mlb = ((((size_t)c * 8 + sh) * 16 + b) * NR + n) * 2;
        const float w = __expf(mlA[mlb] - M);
        L += mlA[mlb + 1] * w;
        const f16* src = oA + ((((size_t)c * 8 + sh) * 16 + b) * NR + n) * 32 + smh * 16;
        #pragma unroll
        for (int j = 0; j < 16; ++j) o[j] += w * (float)src[j];
    }
    const float invL = 1.f / L;
    #pragma unroll
    for (int j = 0; j < 16; ++j) o[j] *= invL;

    if (oB != nullptr) {
        const float invB = 1.f / mlB[(((size_t)sh * 16 + b) * NR + n) * 2 + 1];
        const f16* src = oB + (((size_t)sh * 16 + b) * NR + n) * 32 + smh * 16;
        #pragma unroll
        for (int j = 0; j < 16; ++j) o[j] += invB * (float)src[j];
    }
    float* dst = HE + ((size_t)b * 512 + q_off + n) * 256 + sh * 32 + smh * 16;
    #pragma unroll
    for (int j4 = 0; j4 < 4; ++j4)
        *(float4*)(dst + j4 * 4) = make_float4(o[j4*4+0], o[j4*4+1], o[j4*4+2], o[j4*4+3]);
}

// ---------------------------------------------------------------------------
extern "C" void kernel_launch(void* const* d_in, const int* in_sizes, int n_in,
                              void* d_out, int out_size, void* d_ws, size_t ws_size,
                              hipStream_t stream)
{
    (void)in_sizes; (void)n_in; (void)out_size; (void)ws_size;

    const float* h_fea  = (const float*)d_in[0];
    const float* aux    = (const float*)d_in[1];
    const float* Wq_c   = (const float*)d_in[2];
    const float* Wq_c1  = (const float*)d_in[3];
    const float* Wk_c   = (const float*)d_in[4];
    const float* Wv_c   = (const float*)d_in[5];
    const float* Wq_ch1 = (const float*)d_in[6];
    const float* Wk_ch  = (const float*)d_in[7];
    const float* Wv_ch  = (const float*)d_in[8];
    const float* W1     = (const float*)d_in[9];
    const float* b1     = (const float*)d_in[10];
    const float* W2     = (const float*)d_in[11];
    const float* b2     = (const float*)d_in[12];
    const float* W_out  = (const float*)d_in[13];

    const size_t TBIG = (size_t)8 * 16 * 448 * 32;   // 1,835,008 elems
    const size_t TSML = (size_t)8 * 16 * 64 * 32;    //   262,144 elems
    char* wp = (char*)d_ws;
    auto alloc = [&](size_t bytes) { char* p = wp; wp += (bytes + 255) & ~(size_t)255; return p; };

    f16*   QT1 = (f16*)alloc(TBIG * 2);
    f16*   QT  = (f16*)alloc(TBIG * 2);
    f16*   KC  = (f16*)alloc(TBIG * 2);
    f16*   VCT = (f16*)alloc(TBIG * 2);              // V_c transposed [h][b][e][448]
    f16*   QS  = (f16*)alloc(TSML * 2);
    f16*   KS  = (f16*)alloc(TSML * 2);
    f16*   VST = (f16*)alloc(TSML * 2);              // V_s transposed [h][b][e][64]
    float* HE  = (float*)alloc((size_t)16 * 512 * 256 * 4);
    f16*   oA  = (f16*)alloc(7 * TBIG * 2);
    float* mlA = (float*)alloc((size_t)7 * 8 * 16 * 448 * 2 * 4);
    f16*   oB  = (f16*)alloc(TBIG * 2);
    float* mlB = (float*)alloc((size_t)8 * 16 * 448 * 2 * 4);
    f16*   oC  = (f16*)alloc(7 * TSML * 2);
    float* mlC = (float*)alloc((size_t)7 * 8 * 16 * 64 * 2 * 4);

    // Projections (task rows q 64..511, stat rows q 0..63); V outputs transposed
    // R7: blockIdx.y = p*2 + column-half (64x128 tiles)
    proj_gemm<<<dim3(112, 8), 256, 0, stream>>>(h_fea, Wq_c1, Wq_c, Wk_c, Wv_c,
                                                QT1, QT, KC, VCT, 64, 448, 7, 3);
    proj_gemm<<<dim3(16, 6), 256, 0, stream>>>(h_fea, Wq_ch1, Wk_ch, Wv_ch, Wv_ch,
                                               QS, KS, VST, VST, 0, 64, 1, 2);

    // attend1: task q vs task k (448 keys, 7 chunks of 64)
    attend_mfma<<<dim3(28, 16, 7), 512, 0, stream>>>(QT1, KC, VCT, aux, W1, b1, W2, b2,
                                                     oA, mlA, 448, 448, 64, 64, 64);
    // attend2: task q vs stat k (64 keys, 1 chunk)
    attend_mfma<<<dim3(28, 16, 1), 512, 0, stream>>>(QT, KS, VST, aux, W1, b1, W2, b2,
                                                     oB, mlB, 448, 64, 64, 64, 0);
    // attend3: stat q vs task k (448 keys, 7 chunks of 64)
    attend_mfma<<<dim3(4, 16, 7), 512, 0, stream>>>(QS, KC, VCT, aux, W1, b1, W2, b2,
                                                    oC, mlC, 64, 448, 64, 0, 64);

    // Combine
    combine_kernel<<<dim3(28, 16), 256, 0, stream>>>(oA, mlA, 7, oB, mlB, HE, 448, 64);
    combine_kernel<<<dim3(4, 16), 256, 0, stream>>>(oC, mlC, 7, nullptr, nullptr, HE, 64, 0);

    // h_wave = HEADS[8192,256] @ W_out[256,256]
    out_gemm<<<dim3(128, 2), 256, 0, stream>>>(HE, W_out, (float*)d_out);
}

// Round 8
// 433.147 us; speedup vs baseline: 1.2377x; 1.1359x over previous
//
#include <hip/hip_runtime.h>
#include <math.h>

// Shapes (fixed): H=8, D=256, HD=32, B=16, Q=512, S1=64, NTASK=448
typedef _Float16 f16;
typedef f16  f16x8 __attribute__((ext_vector_type(8)));
typedef f16  f16x4 __attribute__((ext_vector_type(4)));
typedef f16  f16x2 __attribute__((ext_vector_type(2)));
typedef float f32x4 __attribute__((ext_vector_type(4)));

// ---------------------------------------------------------------------------
// Weight transpose+convert: W[h][256 d][32 e] f32  ->  Wt[(mat,h)][e][256 d] f16
// mats 0..3 -> WtBig (Wq_c1, Wq_c, Wk_c, Wv_c), 4..6 -> WtSml (Wq_ch1, Wk_ch,
// Wv_ch).  One-off per launch (~1 MB traffic).
// ---------------------------------------------------------------------------
__global__ __launch_bounds__(256)
void wconv(const float* __restrict__ W0, const float* __restrict__ W1p,
           const float* __restrict__ W2p, const float* __restrict__ W3p,
           const float* __restrict__ W4p, const float* __restrict__ W5p,
           const float* __restrict__ W6p,
           f16* __restrict__ WtBig, f16* __restrict__ WtSml)
{
    __shared__ float Lt[256][33];
    const int tid = (int)threadIdx.x;
    const int mat = (int)blockIdx.x, h = (int)blockIdx.y;
    const float* src =
        (mat==0)?W0:(mat==1)?W1p:(mat==2)?W2p:(mat==3)?W3p:(mat==4)?W4p:(mat==5)?W5p:W6p;
    src += (size_t)h * 256 * 32;
    f16* dst = (mat < 4) ? WtBig + (size_t)(mat*8+h) * 32 * 256
                         : WtSml + (size_t)((mat-4)*8+h) * 32 * 256;
    #pragma unroll
    for (int i = 0; i < 8; ++i) {
        int idx = tid + 256*i;               // 2048 float4 = 256 d x 32 e
        int d = idx >> 3, e4 = (idx & 7) * 4;
        float4 v = *(const float4*)&src[(size_t)d*32 + e4];
        Lt[d][e4] = v.x; Lt[d][e4+1] = v.y; Lt[d][e4+2] = v.z; Lt[d][e4+3] = v.w;
    }
    __syncthreads();
    const int e = tid & 31, db = tid >> 5;
    #pragma unroll
    for (int j = 0; j < 32; ++j) {
        int d = db*32 + j;
        dst[(size_t)e*256 + d] = (f16)Lt[d][e];
    }
}

// ---------------------------------------------------------------------------
// Projection via MFMA (f16 inputs, fp32 accum, f16 out).  R8: the fp32 VALU
// proj was latency-bound (R5 64x64 452us total; R6/R7 denser tiles both
// REGRESSED -> not VALU-bound), and proj outputs were already f16-rounded,
// so f16-input MFMA adds error of the same order as the existing output
// rounding.  Block = 4 waves = one (b, 64-row n-tile, p).  A tile converted
// f32->f16 into LDS (pad to 264: 2-way bank alias = free).  Per wave:
// af[8] hoisted once; 8 h x 2 e-tiles x 8 k = 128 MFMA, dual accumulators.
// B-frags from L2-resident Wt (512KB).  Output layouts identical to fp32
// version: normal [h][b][n][32], V^T (p==vt_p) [h][b][e][NR].
// ---------------------------------------------------------------------------
__global__ __launch_bounds__(256)
void proj_mfma(const float* __restrict__ A, const f16* __restrict__ Wt,
               f16* __restrict__ O0, f16* __restrict__ O1,
               f16* __restrict__ O2, f16* __restrict__ O3,
               int q_off, int rows_per_b, int tiles_per_b, int vt_p)
{
    __shared__ f16 Af[64][264];
    const int tid = (int)threadIdx.x;
    const int b  = (int)blockIdx.x / tiles_per_b;
    const int n0 = ((int)blockIdx.x % tiles_per_b) * 64;
    const int p  = (int)blockIdx.y;
    f16* Op = (p == 0) ? O0 : (p == 1) ? O1 : (p == 2) ? O2 : O3;

    const float* Arow = A + (size_t)(b * 512 + q_off + n0) * 256;
    #pragma unroll
    for (int i = 0; i < 16; ++i) {
        int idx = tid + 256 * i;             // 4096 float4 = 64 rows x 64 chunks
        int row = idx >> 6, c4 = idx & 63;
        float4 v = *(const float4*)&Arow[(size_t)row * 256 + c4 * 4];
        f16x4 hv = { (f16)v.x, (f16)v.y, (f16)v.z, (f16)v.w };
        *(f16x4*)&Af[row][c4 * 4] = hv;
    }
    __syncthreads();

    const int lane = tid & 63, ln = lane & 15, qd = lane >> 4;
    const int w = tid >> 6;

    // A fragments: wave w owns rows w*16 .. w*16+15 (row=ln, k=qd*8..+7)
    f16x8 af[8];
    #pragma unroll
    for (int ks = 0; ks < 8; ++ks)
        af[ks] = *(const f16x8*)&Af[w * 16 + ln][ks * 32 + qd * 8];

    const f16* Wp = Wt + (size_t)p * 8 * 32 * 256;
    #pragma unroll
    for (int h = 0; h < 8; ++h) {
        const f16* Wh = Wp + (size_t)h * 32 * 256;
        f32x4 a0 = {0.f,0.f,0.f,0.f}, a1 = {0.f,0.f,0.f,0.f};
        #pragma unroll
        for (int ks = 0; ks < 8; ++ks) {
            f16x8 b0 = *(const f16x8*)&Wh[(size_t)ln * 256 + ks * 32 + qd * 8];
            f16x8 b1 = *(const f16x8*)&Wh[(size_t)(16 + ln) * 256 + ks * 32 + qd * 8];
            a0 = __builtin_amdgcn_mfma_f32_16x16x32_f16(af[ks], b0, a0, 0, 0, 0);
            a1 = __builtin_amdgcn_mfma_f32_16x16x32_f16(af[ks], b1, a1, 0, 0, 0);
        }
        // D layout: row = qd*4+r, col = ln (m89-verified)
        if (p == vt_p) {
            #pragma unroll
            for (int et = 0; et < 2; ++et) {
                f32x4 a = et ? a1 : a0;
                f16x4 v = { (f16)a[0], (f16)a[1], (f16)a[2], (f16)a[3] };
                *(f16x4*)&Op[(((size_t)h * 16 + b) * 32 + et * 16 + ln) * rows_per_b
                             + n0 + w * 16 + qd * 4] = v;
            }
        } else {
            #pragma unroll
            for (int et = 0; et < 2; ++et) {
                f32x4 a = et ? a1 : a0;
                #pragma unroll
                for (int r = 0; r < 4; ++r)
                    Op[(((size_t)h * 16 + b) * rows_per_b + n0 + w * 16 + qd * 4 + r) * 32
                       + et * 16 + ln] = (f16)a[r];
            }
        }
    }
}

// ---------------------------------------------------------------------------
// Output projection: C[bq][d] = HEADS[8192,256] @ W_out[256,256]  (fp32)
// R8: reverted to the R5 64x64 config (fastest measured; denser tiles
// regressed -> latency-bound, small tiles + 512 blocks win).
// ---------------------------------------------------------------------------
__global__ __launch_bounds__(256)
void out_gemm(const float* __restrict__ A, const float* __restrict__ Bm,
              float* __restrict__ C)
{
    __shared__ float Asub[32][68];
    __shared__ float Bsub[32][68];
    const int tid = (int)threadIdx.x;
    const int row0 = (int)blockIdx.x * 64;
    const int col0 = (int)blockIdx.y * 64;
    const int tx = tid & 15, ty = tid >> 4;
    float acc[4][4] = {};

    for (int k0 = 0; k0 < 256; k0 += 32) {
        #pragma unroll
        for (int i = 0; i < 8; ++i) {
            int idx = tid + 256 * i;
            int kk = idx & 31, r = idx >> 5;
            Asub[kk][r] = A[(size_t)(row0 + r) * 256 + k0 + kk];
        }
        #pragma unroll
        for (int i = 0; i < 8; ++i) {
            int idx = tid + 256 * i;
            int c = idx & 63, kk = idx >> 6;
            Bsub[kk][c] = Bm[(size_t)(k0 + kk) * 256 + col0 + c];
        }
        __syncthreads();
        #pragma unroll
        for (int kk = 0; kk < 32; ++kk) {
            float4 a4 = *(const float4*)&Asub[kk][ty * 4];
            float4 b4 = *(const float4*)&Bsub[kk][tx * 4];
            acc[0][0] += a4.x * b4.x; acc[0][1] += a4.x * b4.y; acc[0][2] += a4.x * b4.z; acc[0][3] += a4.x * b4.w;
            acc[1][0] += a4.y * b4.x; acc[1][1] += a4.y * b4.y; acc[1][2] += a4.y * b4.z; acc[1][3] += a4.y * b4.w;
            acc[2][0] += a4.z * b4.x; acc[2][1] += a4.z * b4.y; acc[2][2] += a4.z * b4.z; acc[2][3] += a4.z * b4.w;
            acc[3][0] += a4.w * b4.x; acc[3][1] += a4.w * b4.y; acc[3][2] += a4.w * b4.z; acc[3][3] += a4.w * b4.w;
        }
        __syncthreads();
    }
    #pragma unroll
    for (int i = 0; i < 4; ++i) {
        float4 v = make_float4(acc[i][0], acc[i][1], acc[i][2], acc[i][3]);
        *(float4*)&C[(size_t)(row0 + ty * 4 + i) * 256 + col0 + tx * 4] = v;
    }
}

// ---------------------------------------------------------------------------
// MFMA attend partial.  512 threads / 8 waves.  16 query rows x 32 keys per
// step, 8 heads.  Wave w owns head w (one head per wave).  K: [h][b][m][32]
// f16.  V^T: [h][b][e][ML] f16.  Scores + P@V via mfma 16x16x32 f16.
// MLP role: 1 position per thread (mn=tid>>5 row, mi=tid&31 key).
// R5 verified: VGPR=56, occupancy 39-40%, no spill, 137us big dispatch.
// ---------------------------------------------------------------------------
__global__ __launch_bounds__(512)
void attend_mfma(const f16* __restrict__ Qb, const f16* __restrict__ Kb,
                 const f16* __restrict__ Vt, const float* __restrict__ aux,
                 const float* __restrict__ W1g, const float* __restrict__ b1g,
                 const float* __restrict__ W2g, const float* __restrict__ b2g,
                 f16* __restrict__ o_part, float* __restrict__ ml_part,
                 int NR, int ML, int KCHUNK, int n_off, int m_off)
{
    __shared__ float Sx[16 * 289];       // [n]*289 + m*9 + h   (m 0..31, h 0..7)
    __shared__ f16   Pb[8 * 16 * 32];    // [h][n][m] f16 (A-frag friendly)
    __shared__ float Wl[408];            // W1(256) | W2(128) | b1(16) | b2(8)
    __shared__ float Alph[128];          // [n][h]
    __shared__ float MLs[256];           // [n][h][{M,L}]

    const int tid   = (int)threadIdx.x;
    const int n0g   = (int)blockIdx.x * 16;
    const int b     = (int)blockIdx.y;
    const int chunk = (int)blockIdx.z;
    const int m_base = chunk * KCHUNK;

    if (tid < 256) Wl[tid] = W1g[tid];
    if (tid >= 256 && tid < 384) Wl[tid] = W2g[tid - 256];
    if (tid >= 384 && tid < 400) Wl[tid] = b1g[tid - 384];
    if (tid >= 400 && tid < 408) Wl[tid] = b2g[tid - 400];
    if (tid < 128) { MLs[tid * 2] = -INFINITY; MLs[tid * 2 + 1] = 0.f; }

    const int lane = tid & 63, ln = lane & 15, qd = lane >> 4;
    const int wid  = tid >> 6;           // head owned by this wave (0..7)
    const int mn = tid >> 5, mi = tid & 31;

    f16x8 qf = *(const f16x8*)(Qb + ((((size_t)wid * 16 + b) * NR + n0g + ln) * 32) + qd * 8);

    f32x4 oacc[2];
    oacc[0] = (f32x4){0.f, 0.f, 0.f, 0.f};
    oacc[1] = (f32x4){0.f, 0.f, 0.f, 0.f};

    const size_t aux_row = ((size_t)b * 512 + (n_off + n0g + mn)) * 512 + m_off;
    float auxr[8];
    #pragma unroll
    for (int h = 0; h < 8; ++h)
        auxr[h] = aux[(size_t)h * 16 * 512 * 512 + aux_row + m_base + mi];
    __syncthreads();

    for (int m0 = m_base; m0 < m_base + KCHUNK; m0 += 32) {
        // ---- phase A: scores via MFMA, scatter C-frags to Sx ----
        #pragma unroll
        for (int mt = 0; mt < 2; ++mt) {
            f16x8 kf = *(const f16x8*)(Kb + ((((size_t)wid * 16 + b) * ML + m0 + mt * 16 + ln) * 32) + qd * 8);
            f32x4 c = __builtin_amdgcn_mfma_f32_16x16x32_f16(qf, kf, (f32x4){0.f,0.f,0.f,0.f}, 0, 0, 0);
            #pragma unroll
            for (int r = 0; r < 4; ++r)
                Sx[(qd * 4 + r) * 289 + (mt * 16 + ln) * 9 + wid] = c[r];
        }
        __syncthreads();

        // ---- phase B: fused MLP (1 position/thread) + online softmax ----
        {
            float Mold[8];
            #pragma unroll
            for (int h = 0; h < 8; ++h) Mold[h] = MLs[(mn * 8 + h) * 2];

            float x[16];
            #pragma unroll
            for (int h = 0; h < 8; ++h) {
                x[h]     = Sx[mn * 289 + mi * 9 + h];
                x[8 + h] = auxr[h];
            }
            float hid[16];
            #pragma unroll
            for (int j = 0; j < 16; ++j) hid[j] = Wl[384 + j];
            #pragma unroll
            for (int i = 0; i < 16; ++i) {
                const float a = x[i];
                #pragma unroll
                for (int j = 0; j < 16; ++j) hid[j] += a * Wl[i * 16 + j];
            }
            float f[8];
            #pragma unroll
            for (int o = 0; o < 8; ++o) f[o] = Wl[400 + o];
            #pragma unroll
            for (int j = 0; j < 16; ++j) {
                const float g = fmaxf(hid[j], 0.f);
                #pragma unroll
                for (int o = 0; o < 8; ++o) f[o] += g * Wl[256 + j * 8 + o];
            }
            float rmax[8];
            #pragma unroll
            for (int h = 0; h < 8; ++h) rmax[h] = f[h];
            #pragma unroll
            for (int d = 1; d < 32; d <<= 1)
                #pragma unroll
                for (int h = 0; h < 8; ++h) rmax[h] = fmaxf(rmax[h], __shfl_xor(rmax[h], d));
            float alr[8], rsum[8];
            #pragma unroll
            for (int h = 0; h < 8; ++h) {
                const float nM = fmaxf(Mold[h], rmax[h]);
                alr[h] = __expf(Mold[h] - nM);
                const float e = __expf(f[h] - nM);
                f[h] = e;
                rsum[h] = e;
            }
            #pragma unroll
            for (int d = 1; d < 32; d <<= 1)
                #pragma unroll
                for (int h = 0; h < 8; ++h) rsum[h] += __shfl_xor(rsum[h], d);
            #pragma unroll
            for (int h = 0; h < 8; ++h)
                Pb[((size_t)h * 16 + mn) * 32 + mi] = (f16)f[h];
            if (mi == 0) {
                #pragma unroll
                for (int h = 0; h < 8; ++h) {
                    const int ix = (mn * 8 + h) * 2;
                    const float nM = fmaxf(Mold[h], rmax[h]);
                    const float Lold = MLs[ix + 1];
                    MLs[ix]     = nM;
                    MLs[ix + 1] = Lold * alr[h] + rsum[h];
                    Alph[mn * 8 + h] = alr[h];
                }
            }
            if (m0 + 32 < m_base + KCHUNK) {
                #pragma unroll
                for (int h = 0; h < 8; ++h)
                    auxr[h] = aux[(size_t)h * 16 * 512 * 512 + aux_row + m0 + 32 + mi];
            }
        }
        __syncthreads();

        // ---- phase C: rescale accumulator, P @ V via MFMA ----
        {
            float al[4];
            #pragma unroll
            for (int r = 0; r < 4; ++r) al[r] = Alph[(qd * 4 + r) * 8 + wid];
            f16x8 pf = *(const f16x8*)&Pb[((size_t)wid * 16 + ln) * 32 + qd * 8];
            #pragma unroll
            for (int hf = 0; hf < 2; ++hf) {
                f16x8 vf = *(const f16x8*)(Vt + ((((size_t)wid * 16 + b) * 32 + hf * 16 + ln) * ML) + m0 + qd * 8);
                f32x4 c = oacc[hf];
                #pragma unroll
                for (int r = 0; r < 4; ++r) c[r] *= al[r];
                oacc[hf] = __builtin_amdgcn_mfma_f32_16x16x32_f16(pf, vf, c, 0, 0, 0);
            }
        }
    }

    // ---- epilogue: unnormalized o (f16), (m,l) fp32 ----
    #pragma unroll
    for (int hf = 0; hf < 2; ++hf)
        #pragma unroll
        for (int r = 0; r < 4; ++r)
            o_part[(((((size_t)chunk * 8 + wid) * 16 + b) * NR + n0g + qd * 4 + r) * 32) + hf * 16 + ln]
                = (f16)oacc[hf][r];
    if (mi == 0) {
        #pragma unroll
        for (int h = 0; h < 8; ++h) {
            const size_t base = ((((size_t)chunk * 8 + h) * 16 + b) * NR + n0g + mn) * 2;
            ml_part[base]     = MLs[(mn * 8 + h) * 2];
            ml_part[base + 1] = MLs[(mn * 8 + h) * 2 + 1];
        }
    }
}

// ---------------------------------------------------------------------------
// Combine: merge nchA key-chunks (shared softmax) + optional group-B partial
// (independent softmax, added). Writes HE[b][q_off+n][h*32+e] fp32.
// ---------------------------------------------------------------------------
__global__ __launch_bounds__(256)
void combine_kernel(const f16* __restrict__ oA, const float* __restrict__ mlA, int nchA,
                    const f16* __restrict__ oB, const float* __restrict__ mlB,
                    float* __restrict__ HE, int NR, int q_off)
{
    const int tid = (int)threadIdx.x;
    const int sn = tid >> 4, sh = (tid >> 1) & 7, smh = tid & 1;
    const int n = (int)blockIdx.x * 16 + sn;
    const int b = (int)blockIdx.y;

    float M = -INFINITY;
    for (int c = 0; c < nchA; ++c)
        M = fmaxf(M, mlA[((((size_t)c * 8 + sh) * 16 + b) * NR + n) * 2]);
    float L = 0.f;
    float o[16];
    #pragma unroll
    for (int j = 0; j < 16; ++j) o[j] = 0.f;
    for (int c = 0; c < nchA; ++c) {
        const size_t mlb = ((((size_t)c * 8 + sh) * 16 + b) * NR + n) * 2;
        const float w = __expf(mlA[mlb] - M);
        L += mlA[mlb + 1] * w;
        const f16* src = oA + ((((size_t)c * 8 + sh) * 16 + b) * NR + n) * 32 + smh * 16;
        #pragma unroll
        for (int j = 0; j < 16; ++j) o[j] += w * (float)src[j];
    }
    const float invL = 1.f / L;
    #pragma unroll
    for (int j = 0; j < 16; ++j) o[j] *= invL;

    if (oB != nullptr) {
        const float invB = 1.f / mlB[(((size_t)sh * 16 + b) * NR + n) * 2 + 1];
        const f16* src = oB + (((size_t)sh * 16 + b) * NR + n) * 32 + smh * 16;
        #pragma unroll
        for (int j = 0; j < 16; ++j) o[j] += invB * (float)src[j];
    }
    float* dst = HE + ((size_t)b * 512 + q_off + n) * 256 + sh * 32 + smh * 16;
    #pragma unroll
    for (int j4 = 0; j4 < 4; ++j4)
        *(float4*)(dst + j4 * 4) = make_float4(o[j4*4+0], o[j4*4+1], o[j4*4+2], o[j4*4+3]);
}

// ---------------------------------------------------------------------------
extern "C" void kernel_launch(void* const* d_in, const int* in_sizes, int n_in,
                              void* d_out, int out_size, void* d_ws, size_t ws_size,
                              hipStream_t stream)
{
    (void)in_sizes; (void)n_in; (void)out_size; (void)ws_size;

    const float* h_fea  = (const float*)d_in[0];
    const float* aux    = (const float*)d_in[1];
    const float* Wq_c   = (const float*)d_in[2];
    const float* Wq_c1  = (const float*)d_in[3];
    const float* Wk_c   = (const float*)d_in[4];
    const float* Wv_c   = (const float*)d_in[5];
    const float* Wq_ch1 = (const float*)d_in[6];
    const float* Wk_ch  = (const float*)d_in[7];
    const float* Wv_ch  = (const float*)d_in[8];
    const float* W1     = (const float*)d_in[9];
    const float* b1     = (const float*)d_in[10];
    const float* W2     = (const float*)d_in[11];
    const float* b2     = (const float*)d_in[12];
    const float* W_out  = (const float*)d_in[13];

    const size_t TBIG = (size_t)8 * 16 * 448 * 32;   // 1,835,008 elems
    const size_t TSML = (size_t)8 * 16 * 64 * 32;    //   262,144 elems
    char* wp = (char*)d_ws;
    auto alloc = [&](size_t bytes) { char* p = wp; wp += (bytes + 255) & ~(size_t)255; return p; };

    f16*   QT1 = (f16*)alloc(TBIG * 2);
    f16*   QT  = (f16*)alloc(TBIG * 2);
    f16*   KC  = (f16*)alloc(TBIG * 2);
    f16*   VCT = (f16*)alloc(TBIG * 2);              // V_c transposed [h][b][e][448]
    f16*   QS  = (f16*)alloc(TSML * 2);
    f16*   KS  = (f16*)alloc(TSML * 2);
    f16*   VST = (f16*)alloc(TSML * 2);              // V_s transposed [h][b][e][64]
    float* HE  = (float*)alloc((size_t)16 * 512 * 256 * 4);
    f16*   oA  = (f16*)alloc(7 * TBIG * 2);
    float* mlA = (float*)alloc((size_t)7 * 8 * 16 * 448 * 2 * 4);
    f16*   oB  = (f16*)alloc(TBIG * 2);
    float* mlB = (float*)alloc((size_t)8 * 16 * 448 * 2 * 4);
    f16*   oC  = (f16*)alloc(7 * TSML * 2);
    float* mlC = (float*)alloc((size_t)7 * 8 * 16 * 64 * 2 * 4);
    f16*   WtBig = (f16*)alloc((size_t)4 * 8 * 32 * 256 * 2);   // [p][h][e][d] f16
    f16*   WtSml = (f16*)alloc((size_t)3 * 8 * 32 * 256 * 2);

    // Weight transpose+convert (one-off)
    wconv<<<dim3(7, 8), 256, 0, stream>>>(Wq_c1, Wq_c, Wk_c, Wv_c,
                                          Wq_ch1, Wk_ch, Wv_ch, WtBig, WtSml);

    // Projections via MFMA (task rows q 64..511, stat rows q 0..63)
    proj_mfma<<<dim3(112, 4), 256, 0, stream>>>(h_fea, WtBig, QT1, QT, KC, VCT,
                                                64, 448, 7, 3);
    proj_mfma<<<dim3(16, 3), 256, 0, stream>>>(h_fea, WtSml, QS, KS, VST, VST,
                                               0, 64, 1, 2);

    // attend1: task q vs task k (448 keys, 7 chunks of 64)
    attend_mfma<<<dim3(28, 16, 7), 512, 0, stream>>>(QT1, KC, VCT, aux, W1, b1, W2, b2,
                                                     oA, mlA, 448, 448, 64, 64, 64);
    // attend2: task q vs stat k (64 keys, 1 chunk)
    attend_mfma<<<dim3(28, 16, 1), 512, 0, stream>>>(QT, KS, VST, aux, W1, b1, W2, b2,
                                                     oB, mlB, 448, 64, 64, 64, 0);
    // attend3: stat q vs task k (448 keys, 7 chunks of 64)
    attend_mfma<<<dim3(4, 16, 7), 512, 0, stream>>>(QS, KC, VCT, aux, W1, b1, W2, b2,
                                                    oC, mlC, 64, 448, 64, 0, 64);

    // Combine
    combine_kernel<<<dim3(28, 16), 256, 0, stream>>>(oA, mlA, 7, oB, mlB, HE, 448, 64);
    combine_kernel<<<dim3(4, 16), 256, 0, stream>>>(oC, mlC, 7, nullptr, nullptr, HE, 64, 0);

    // h_wave = HEADS[8192,256] @ W_out[256,256]  (fp32, R5 64x64 config)
    out_gemm<<<dim3(128, 4), 256, 0, stream>>>(HE, W_out, (float*)d_out);
}